// Round 10
// baseline (285.862 us; speedup 1.0000x reference)
//
#include <hip/hip_runtime.h>

typedef __attribute__((ext_vector_type(8))) short short8;
typedef __attribute__((ext_vector_type(4))) float f32x4;

#define N_TOK   16384
#define HDIM    1024
#define OUT_OFF 16777216   // 16384*1024
#define M1ROWS  26216      // 2*(2097+11011)
#define M2ROWS  22022      // 2*11011
#define L2ROW0  4194       // 2*2097

__device__ __forceinline__ unsigned short f2bf(float f) {
  unsigned int u = __float_as_uint(f);
  u += 0x7FFFu + ((u >> 16) & 1u);
  return (unsigned short)(u >> 16);
}

__device__ __forceinline__ void rowmap(int r, int& is_v, int& rank) {
  if (r < 2097)       { is_v = 0; rank = 3276 + r; }
  else if (r < 4194)  { is_v = 1; rank = 1179 + r; }
  else if (r < 15205) { is_v = 0; rank = 1179 + r; }
  else                { is_v = 1; rank = r - 9832; }
}

// ---- stable descending rank ----
__global__ __launch_bounds__(256) void rank_count(const float* __restrict__ imp,
                                                  int* __restrict__ counts) {
  __shared__ float sj[2048];
  const int i = blockIdx.x * 256 + threadIdx.x;
  const int jbase = blockIdx.y * 2048;
  const float vi = imp[i];
  for (int s = threadIdx.x; s < 2048; s += 256) sj[s] = imp[jbase + s];
  __syncthreads();
  int cnt = 0;
  #pragma unroll 8
  for (int s = 0; s < 2048; ++s) {
    float vj = sj[s];
    bool gt = vj > vi;
    bool eq = (vj == vi) && ((jbase + s) < i);
    cnt += (gt || eq) ? 1 : 0;
  }
  atomicAdd(&counts[i], cnt);
}

__global__ __launch_bounds__(256) void scatter_order(const int* __restrict__ counts,
                                                     int* __restrict__ order) {
  int i = blockIdx.x * 256 + threadIdx.x;
  order[counts[i]] = i;
}

// ---- all 4 weight converts in ONE launch: dst[N][K] bf16 transposed+padded ----
__global__ __launch_bounds__(256) void wconv4(
    unsigned short* __restrict__ We0T, const float* __restrict__ We0,
    unsigned short* __restrict__ We1T, const float* __restrict__ We1,
    unsigned short* __restrict__ Wd1T, const float* __restrict__ Wd1,
    unsigned short* __restrict__ Wd0T, const float* __restrict__ Wd0) {
  int b = blockIdx.x;
  unsigned short* dst; const float* src; int Kd, Nsrc, Ksrc, idx;
  if (b < 2048)      { dst = We0T; src = We0; Kd = 1024; Nsrc = 512;  Ksrc = 1024; idx = b * 256 + threadIdx.x; }
  else if (b < 2560) { dst = We1T; src = We1; Kd = 512;  Nsrc = 204;  Ksrc = 512;  idx = (b - 2048) * 256 + threadIdx.x; }
  else if (b < 3072) { dst = Wd1T; src = Wd1; Kd = 256;  Nsrc = 512;  Ksrc = 204;  idx = (b - 2560) * 256 + threadIdx.x; }
  else               { dst = Wd0T; src = Wd0; Kd = 512;  Nsrc = 1024; Ksrc = 512;  idx = (b - 3072) * 256 + threadIdx.x; }
  int n = idx / Kd, k = idx % Kd;
  float v = (n < Nsrc && k < Ksrc) ? src[k * Nsrc + n] : 0.f;
  dst[idx] = f2bf(v);
}

__global__ __launch_bounds__(256) void copy_level0(float* __restrict__ out,
                                                   const float* __restrict__ keys,
                                                   const float* __restrict__ values,
                                                   const int* __restrict__ order) {
  int b = blockIdx.x;
  int is_v = b & 1, rank = b >> 1;
  int token = order[rank];
  const float* src = (is_v ? values : keys) + (size_t)token * HDIM;
  float* dst = out + (is_v ? OUT_OFF : 0) + (size_t)token * HDIM;
  int c = threadIdx.x * 4;
  *reinterpret_cast<float4*>(dst + c) = *reinterpret_cast<const float4*>(src + c);
}

#define GLDS16(g, l) __builtin_amdgcn_global_load_lds( \
    (const __attribute__((address_space(1))) void*)(g), \
    (__attribute__((address_space(3))) void*)(l), 16, 0, 0)

// ---- GEMM1 FUSED with gather: Y = relu(gathered(keys/values) @ We0 + be0) ----
// 128x128 tile, 4 waves, BK=32, 3-slot ring (48 KB -> 3 blocks/CU).
// A is reg-staged straight from f32 keys/values via order[]+rowmap (per-lane
// source addresses), cvt f32->bf16 in-register (same f2bf as the old gather),
// then ds_write_b128 into the XOR-swizzled LDS layout (reg-staging may
// swizzle the dest). B staged via global_load_lds (pre-swizzled source).
// A ds_writes/B GLDS for half h+3 are issued AFTER the barrier that retires
// all reads of slot h%3 -> race-free, 1 barrier per iteration.
// vmcnt: counted (6) mid-loop, drains B(h+1); compiler handles the f32 bank.
template<int K>
__global__ __launch_bounds__(256, 3) void g1f(
    const float* __restrict__ keys, const float* __restrict__ values,
    const int* __restrict__ order, int M,
    const unsigned short* __restrict__ Bt, int N,
    const float* __restrict__ bias,
    unsigned short* __restrict__ Y, int ldc, int NP, int NC) {
  constexpr int NH = K / 32;
  __shared__ __align__(16) unsigned short S[3][8192];  // slot: A[128][32] | B[128][32]

  const int bid = blockIdx.x;
  const int r8 = bid & 7, rest = bid >> 3;
  const int c8 = rest % NC, q8 = rest / NC;
  const int p8 = q8 * 8 + r8;
  if (p8 >= NP) return;
  const int row0 = p8 * 128, col0 = c8 * 128;

  const int tid = threadIdx.x;
  const int wave = tid >> 6, lane = tid & 63;
  const int wm = wave >> 1, wn = wave & 1;
  const int fr = lane & 15, lch = lane >> 4;

  // staging lane geometry: seg = 16 rows x 32 k; row-in-seg, content chunk
  const int rin = lane >> 2;
  const int qc = lane & 3;
  const int xr = (lane >> 3) & 3;           // = (rin>>1)&3, swizzle key
  const int pchunk = qc ^ xr;               // involution

  // A: 2 segs/wave, per-lane f32 source through order[]+rowmap (loop-invariant)
  const float* asrc[2]; int awoff[2];
  #pragma unroll
  for (int j = 0; j < 2; ++j) {
    int s = wave * 2 + j;                   // A segs 0..7
    int gr = row0 + s * 16 + rin; if (gr >= M) gr = 0;
    int iv, rk; rowmap(gr, iv, rk);
    int token = order[rk];
    asrc[j] = (iv ? values : keys) + (size_t)token * HDIM + qc * 8;  // content col
    awoff[j] = (s * 16 + rin) * 32 + pchunk * 8;                     // swizzled dest
  }
  // B: 2 segs/wave via GLDS (linear dest, pre-swizzled source)
  const unsigned short* bsrc[2]; int bldso[2];
  #pragma unroll
  for (int j = 0; j < 2; ++j) {
    int s = wave * 2 + j;
    int cr = col0 + s * 16 + rin; if (cr >= N) cr = 0;
    bsrc[j] = Bt + (size_t)cr * K + pchunk * 8;   // content for phys slot qc
    bldso[j] = 4096 + s * 512;
  }

  // fragment-read geometry
  const int qoff = ((lch ^ ((fr >> 1) & 3)) << 3);
  const int abase = (wm * 64 + fr) * 32 + qoff;
  const int bbase = 4096 + (wn * 64 + fr) * 32 + qoff;

  f32x4 acc[4][4] = {};
  float4 pa[2][2];                          // f32 bank (static indices only)

  // ---- prologue: halves 0..2 into slots 0..2 ----
  #pragma unroll
  for (int hp = 0; hp < 3; ++hp) {
    #pragma unroll
    for (int j = 0; j < 2; ++j) {
      float4 lo = *reinterpret_cast<const float4*>(asrc[j] + hp * 32);
      float4 hi = *reinterpret_cast<const float4*>(asrc[j] + hp * 32 + 4);
      uint4 wv;
      wv.x = (unsigned)f2bf(lo.x) | ((unsigned)f2bf(lo.y) << 16);
      wv.y = (unsigned)f2bf(lo.z) | ((unsigned)f2bf(lo.w) << 16);
      wv.z = (unsigned)f2bf(hi.x) | ((unsigned)f2bf(hi.y) << 16);
      wv.w = (unsigned)f2bf(hi.z) | ((unsigned)f2bf(hi.w) << 16);
      *reinterpret_cast<uint4*>(&S[hp][awoff[j]]) = wv;
    }
  }
  #pragma unroll
  for (int hp = 0; hp < 3; ++hp)
    #pragma unroll
    for (int j = 0; j < 2; ++j)
      GLDS16(bsrc[j] + hp * 32, (unsigned short*)S[hp] + bldso[j]);
  asm volatile("s_waitcnt vmcnt(0)" ::: "memory");
  #pragma unroll
  for (int j = 0; j < 2; ++j) {             // bank = A(3)
    pa[j][0] = *reinterpret_cast<const float4*>(asrc[j] + 3 * 32);
    pa[j][1] = *reinterpret_cast<const float4*>(asrc[j] + 3 * 32 + 4);
  }
  asm volatile("s_waitcnt lgkmcnt(0)" ::: "memory");
  __builtin_amdgcn_s_barrier();

  int sh = 0;
  #pragma unroll 1
  for (int h = 0; h < NH; ++h) {
    const unsigned short* sl = S[sh];
    short8 a[4], b[4];
    #pragma unroll
    for (int m = 0; m < 4; ++m)
      a[m] = *reinterpret_cast<const short8*>(sl + abase + m * 512);
    #pragma unroll
    for (int n = 0; n < 4; ++n)
      b[n] = *reinterpret_cast<const short8*>(sl + bbase + n * 512);
    asm volatile("s_waitcnt lgkmcnt(0)" ::: "memory");   // reads + prev ds_writes drained
    __builtin_amdgcn_sched_barrier(0);
    if (h + 3 < NH) asm volatile("s_waitcnt vmcnt(6)" ::: "memory");  // B(h+1) landed
    else            asm volatile("s_waitcnt vmcnt(0)" ::: "memory");
    __builtin_amdgcn_sched_barrier(0);
    __builtin_amdgcn_s_barrier();            // slot sh fully retired block-wide
    __builtin_amdgcn_s_setprio(1);
    #pragma unroll
    for (int m = 0; m < 4; ++m)
      #pragma unroll
      for (int n = 0; n < 4; ++n)
        acc[m][n] = __builtin_amdgcn_mfma_f32_16x16x32_bf16(a[m], b[n], acc[m][n], 0, 0, 0);
    __builtin_amdgcn_s_setprio(0);
    if (h + 3 < NH) {                        // refill freed slot sh with half h+3
      #pragma unroll
      for (int j = 0; j < 2; ++j) {
        uint4 wv;
        wv.x = (unsigned)f2bf(pa[j][0].x) | ((unsigned)f2bf(pa[j][0].y) << 16);
        wv.y = (unsigned)f2bf(pa[j][0].z) | ((unsigned)f2bf(pa[j][0].w) << 16);
        wv.z = (unsigned)f2bf(pa[j][1].x) | ((unsigned)f2bf(pa[j][1].y) << 16);
        wv.w = (unsigned)f2bf(pa[j][1].z) | ((unsigned)f2bf(pa[j][1].w) << 16);
        *reinterpret_cast<uint4*>(&S[sh][awoff[j]]) = wv;
      }
      if (h + 4 < NH) {
        #pragma unroll
        for (int j = 0; j < 2; ++j) {        // issue bank A(h+4) (before GLDS)
          pa[j][0] = *reinterpret_cast<const float4*>(asrc[j] + (h + 4) * 32);
          pa[j][1] = *reinterpret_cast<const float4*>(asrc[j] + (h + 4) * 32 + 4);
        }
      }
      #pragma unroll
      for (int j = 0; j < 2; ++j)
        GLDS16(bsrc[j] + (h + 3) * 32, (unsigned short*)S[sh] + bldso[j]);
    }
    sh = (sh == 2) ? 0 : sh + 1;
  }

  const int orow = lch * 4;
  #pragma unroll
  for (int m = 0; m < 4; ++m)
    #pragma unroll
    for (int n = 0; n < 4; ++n)
      #pragma unroll
      for (int j = 0; j < 4; ++j) {
        int r = row0 + wm * 64 + m * 16 + orow + j;
        int c = col0 + wn * 64 + n * 16 + fr;
        if (r < M) {
          float v = acc[m][n][j] + bias[c];
          Y[(size_t)r * ldc + c] = f2bf(fmaxf(v, 0.f));
        }
      }
}

// ---- tiled bf16 GEMM (R9/R6 core): 256x128, 8 waves, BK=32, 3-slot ring ----
// MODE 0: bf16 store. MODE 1: LDS-staged f32x4 scatter via rowmap/order.
template<int MODE, int K>
__global__ __launch_bounds__(512, 4) void g2(
    const unsigned short* __restrict__ A, int M,
    const unsigned short* __restrict__ Bt, int N,
    const float* __restrict__ bias, int Nbias,
    unsigned short* __restrict__ Cbf, int ldc,
    float* __restrict__ outf, const int* __restrict__ order,
    int NP, int NC) {
  constexpr int NH = K / 32;
  __shared__ __align__(16) unsigned short S[3][12288];

  const int bid = blockIdx.x;
  const int r8 = bid & 7, rest = bid >> 3;
  const int c8 = rest % NC, q8 = rest / NC;
  const int p8 = q8 * 8 + r8;
  if (p8 >= NP) return;
  const int row0 = p8 * 256, col0 = c8 * 128;

  const int tid = threadIdx.x;
  const int wave = tid >> 6, lane = tid & 63;
  const int wm = wave >> 1, wn = wave & 1;
  const int fr = lane & 15, lch = lane >> 4;

  const int lrow = lane >> 2;
  const int sswz = (((lane & 3) ^ ((lane >> 3) & 3)) << 3);
  const unsigned short* gp[3];
  int ldso[3];
  #pragma unroll
  for (int j = 0; j < 3; ++j) {
    const int g = wave * 3 + j;
    const bool isA = g < 16;
    int rr = isA ? (row0 + g * 16 + lrow) : (col0 + (g - 16) * 16 + lrow);
    const int lim = isA ? M : N;
    if (rr >= lim) rr = 0;
    gp[j] = (isA ? A : Bt) + (size_t)rr * K + sswz;
    ldso[j] = g * 512;
  }

  const int qoff = ((lch ^ ((fr >> 1) & 3)) << 3);
  const int abase = (wm * 64 + fr) * 32 + qoff;
  const int bbase = 8192 + (wn * 64 + fr) * 32 + qoff;

  f32x4 acc[4][4] = {};

  #pragma unroll
  for (int h = 0; h < 3; ++h)
    #pragma unroll
    for (int j = 0; j < 3; ++j)
      GLDS16(gp[j] + h * 32, S[h] + ldso[j]);
  asm volatile("s_waitcnt vmcnt(6)" ::: "memory");
  __builtin_amdgcn_s_barrier();

  int cur = 0;
  #pragma unroll 1
  for (int h = 0; h < NH; ++h) {
    const unsigned short* sl = S[cur];
    short8 a[4], b[4];
    #pragma unroll
    for (int m = 0; m < 4; ++m)
      a[m] = *reinterpret_cast<const short8*>(sl + abase + m * 512);
    #pragma unroll
    for (int n = 0; n < 4; ++n)
      b[n] = *reinterpret_cast<const short8*>(sl + bbase + n * 512);
    asm volatile("s_waitcnt lgkmcnt(0)" ::: "memory");
    __builtin_amdgcn_sched_barrier(0);
    __builtin_amdgcn_s_barrier();
    __builtin_amdgcn_s_setprio(1);
    #pragma unroll
    for (int m = 0; m < 4; ++m)
      #pragma unroll
      for (int n = 0; n < 4; ++n)
        acc[m][n] = __builtin_amdgcn_mfma_f32_16x16x32_bf16(a[m], b[n], acc[m][n], 0, 0, 0);
    __builtin_amdgcn_s_setprio(0);
    if (h + 3 < NH) {
      const int kc = (h + 3) * 32;
      #pragma unroll
      for (int j = 0; j < 3; ++j) GLDS16(gp[j] + kc, S[cur] + ldso[j]);
      asm volatile("s_waitcnt vmcnt(6)" ::: "memory");
    } else if (h + 2 < NH) {
      asm volatile("s_waitcnt vmcnt(3)" ::: "memory");
    } else if (h + 1 < NH) {
      asm volatile("s_waitcnt vmcnt(0)" ::: "memory");
    }
    __builtin_amdgcn_s_barrier();
    cur = (cur == 2) ? 0 : cur + 1;
  }

  const int orow = lch * 4;
  if (MODE == 0) {
    #pragma unroll
    for (int m = 0; m < 4; ++m)
      #pragma unroll
      for (int n = 0; n < 4; ++n)
        #pragma unroll
        for (int j = 0; j < 4; ++j) {
          int r = row0 + wm * 64 + m * 16 + orow + j;
          int c = col0 + wn * 64 + n * 16 + fr;
          if (r < M && c < N) {
            float v = acc[m][n][j] + (c < Nbias ? bias[c] : 0.f);
            Cbf[(size_t)r * ldc + c] = f2bf(fmaxf(v, 0.f));
          }
        }
  } else {
    float* Cl = (float*)S;                           // [64][132] f32
    #pragma unroll 1
    for (int p = 0; p < 4; ++p) {
      __builtin_amdgcn_s_barrier();
      if (wm == p) {
        #pragma unroll
        for (int m = 0; m < 4; ++m)
          #pragma unroll
          for (int n = 0; n < 4; ++n)
            #pragma unroll
            for (int j = 0; j < 4; ++j) {
              int rr = m * 16 + orow + j;
              int cc = wn * 64 + n * 16 + fr;
              float v = acc[m][n][j] + bias[col0 + cc];
              Cl[rr * 132 + cc] = fmaxf(v, 0.f);
            }
      }
      __builtin_amdgcn_s_barrier();
      #pragma unroll
      for (int u = 0; u < 4; ++u) {
        int unit = tid + u * 512;
        int rr = unit >> 5, ch = unit & 31;
        int r = row0 + p * 64 + rr;
        if (r < M) {
          int iv, rk; rowmap(r, iv, rk);
          int token = order[rk];
          f32x4 v = *reinterpret_cast<const f32x4*>(Cl + rr * 132 + ch * 4);
          *reinterpret_cast<f32x4*>(outf + (size_t)(iv ? OUT_OFF : 0) +
                                    (size_t)token * HDIM + col0 + ch * 4) = v;
        }
      }
    }
  }
}

static inline int swzg(int NP, int NC) { return 8 * NC * ((NP + 7) / 8); }

extern "C" void kernel_launch(void* const* d_in, const int* in_sizes, int n_in,
                              void* d_out, int out_size, void* d_ws, size_t ws_size,
                              hipStream_t stream) {
  const float* keys   = (const float*)d_in[0];
  const float* values = (const float*)d_in[1];
  const float* imp    = (const float*)d_in[2];
  const float* We0    = (const float*)d_in[3];
  const float* be0    = (const float*)d_in[4];
  const float* We1    = (const float*)d_in[5];
  const float* be1    = (const float*)d_in[6];
  const float* Wd0    = (const float*)d_in[7];
  const float* bd0    = (const float*)d_in[8];
  const float* Wd1    = (const float*)d_in[9];
  const float* bd1    = (const float*)d_in[10];

  char* ws = (char*)d_ws;
  int* counts           = (int*)(ws);                       // 64 KB
  int* order            = (int*)(ws + 65536);               // 64 KB
  unsigned short* We0T  = (unsigned short*)(ws + 131072);   // [512][1024]
  unsigned short* We1T  = (unsigned short*)(ws + 1179648);  // [256][512], rows 204+ zero
  unsigned short* Wd1T  = (unsigned short*)(ws + 1441792);  // [512][256], cols 204+ zero
  unsigned short* Wd0T  = (unsigned short*)(ws + 1703936);  // [1024][512]
  unsigned short* Y     = (unsigned short*)(ws + 2752512);  // [26216][512]
  unsigned short* Z     = (unsigned short*)(ws + 29597696); // [22022][256]
  float* outf = (float*)d_out;

  hipMemsetAsync(counts, 0, 65536, stream);
  rank_count<<<dim3(64, 8), 256, 0, stream>>>(imp, counts);
  scatter_order<<<64, 256, 0, stream>>>(counts, order);

  wconv4<<<5120, 256, 0, stream>>>(We0T, We0, We1T, We1, Wd1T, Wd1, Wd0T, Wd0);
  copy_level0<<<6552, 256, 0, stream>>>(outf, keys, values, order);

  // GEMM1 (fused gather): Y = relu(gather(keys/values) @ We0 + be0)
  g1f<1024><<<swzg(205, 4), 256, 0, stream>>>(
      keys, values, order, M1ROWS, We0T, 512, be0, Y, 512, 205, 4);

  // GEMM2a: Z = relu(Y_l2 @ We1 + be1)  [22022 x 512] x [512 x 256pad]
  g2<0, 512><<<swzg(87, 2), 512, 0, stream>>>(
      Y + (size_t)L2ROW0 * 512, M2ROWS, We1T, 256, be1, 204, Z, 256,
      nullptr, nullptr, 87, 2);

  // GEMM2b: Y_l2 = relu(Z @ Wd1 + bd1)  [22022 x 256] x [256 x 512]
  g2<0, 256><<<swzg(87, 4), 512, 0, stream>>>(
      Z, M2ROWS, Wd1T, 512, bd1, 512, Y + (size_t)L2ROW0 * 512, 512,
      nullptr, nullptr, 87, 4);

  // GEMM3: out = relu(Y @ Wd0 + bd0), LDS-staged f32x4 scatter
  g2<1, 512><<<swzg(103, 8), 512, 0, stream>>>(
      Y, M1ROWS, Wd0T, 1024, bd0, 1024, nullptr, 0, outf, order, 103, 8);
}

// Round 11
// 271.294 us; speedup vs baseline: 1.0537x; 1.0537x over previous
//
#include <hip/hip_runtime.h>

typedef __attribute__((ext_vector_type(8))) short short8;
typedef __attribute__((ext_vector_type(4))) float f32x4;

#define N_TOK   16384
#define HDIM    1024
#define OUT_OFF 16777216   // 16384*1024
#define M1ROWS  26216      // 2*(2097+11011)
#define M2ROWS  22022      // 2*11011
#define L2ROW0  4194       // 2*2097

__device__ __forceinline__ unsigned short f2bf(float f) {
  unsigned int u = __float_as_uint(f);
  u += 0x7FFFu + ((u >> 16) & 1u);
  return (unsigned short)(u >> 16);
}

__device__ __forceinline__ void rowmap(int r, int& is_v, int& rank) {
  if (r < 2097)       { is_v = 0; rank = 3276 + r; }
  else if (r < 4194)  { is_v = 1; rank = 1179 + r; }
  else if (r < 15205) { is_v = 0; rank = 1179 + r; }
  else                { is_v = 1; rank = r - 9832; }
}

// ---- stable descending rank ----
__global__ __launch_bounds__(256) void rank_count(const float* __restrict__ imp,
                                                  int* __restrict__ counts) {
  __shared__ float sj[2048];
  const int i = blockIdx.x * 256 + threadIdx.x;
  const int jbase = blockIdx.y * 2048;
  const float vi = imp[i];
  for (int s = threadIdx.x; s < 2048; s += 256) sj[s] = imp[jbase + s];
  __syncthreads();
  int cnt = 0;
  #pragma unroll 8
  for (int s = 0; s < 2048; ++s) {
    float vj = sj[s];
    bool gt = vj > vi;
    bool eq = (vj == vi) && ((jbase + s) < i);
    cnt += (gt || eq) ? 1 : 0;
  }
  atomicAdd(&counts[i], cnt);
}

__global__ __launch_bounds__(256) void scatter_order(const int* __restrict__ counts,
                                                     int* __restrict__ order) {
  int i = blockIdx.x * 256 + threadIdx.x;
  order[counts[i]] = i;
}

// ---- fused prep: 4 weight converts + gather(level>=1 -> bf16 X) + level-0 copy ----
__global__ __launch_bounds__(256) void prep_fused(
    unsigned short* __restrict__ We0T, const float* __restrict__ We0,
    unsigned short* __restrict__ We1T, const float* __restrict__ We1,
    unsigned short* __restrict__ Wd1T, const float* __restrict__ Wd1,
    unsigned short* __restrict__ Wd0T, const float* __restrict__ Wd0,
    unsigned short* __restrict__ X,
    const float* __restrict__ keys, const float* __restrict__ values,
    const int* __restrict__ order, float* __restrict__ out) {
  int b = blockIdx.x;
  if (b < 5120) {            // weight transpose+convert (+zero pad)
    unsigned short* dst; const float* src; int Kd, Nsrc, Ksrc, idx;
    if (b < 2048)      { dst = We0T; src = We0; Kd = 1024; Nsrc = 512;  Ksrc = 1024; idx = b * 256 + threadIdx.x; }
    else if (b < 2560) { dst = We1T; src = We1; Kd = 512;  Nsrc = 204;  Ksrc = 512;  idx = (b - 2048) * 256 + threadIdx.x; }
    else if (b < 3072) { dst = Wd1T; src = Wd1; Kd = 256;  Nsrc = 512;  Ksrc = 204;  idx = (b - 2560) * 256 + threadIdx.x; }
    else               { dst = Wd0T; src = Wd0; Kd = 512;  Nsrc = 1024; Ksrc = 512;  idx = (b - 3072) * 256 + threadIdx.x; }
    int n = idx / Kd, k = idx % Kd;
    float v = (n < Nsrc && k < Ksrc) ? src[k * Nsrc + n] : 0.f;
    dst[idx] = f2bf(v);
  } else if (b < 5120 + M1ROWS) {   // gather level>=1 row -> bf16
    int r = b - 5120;
    int is_v, rank; rowmap(r, is_v, rank);
    int token = order[rank];
    const float* src = (is_v ? values : keys) + (size_t)token * HDIM;
    int c = threadIdx.x * 4;
    float4 f = *reinterpret_cast<const float4*>(src + c);
    ushort4 h;
    h.x = f2bf(f.x); h.y = f2bf(f.y); h.z = f2bf(f.z); h.w = f2bf(f.w);
    *reinterpret_cast<ushort4*>(X + (size_t)r * HDIM + c) = h;
  } else {                          // level-0 exact f32 passthrough
    int bb = b - (5120 + M1ROWS);
    int is_v = bb & 1, rank = bb >> 1;
    int token = order[rank];
    const float* src = (is_v ? values : keys) + (size_t)token * HDIM;
    float* dst = out + (is_v ? OUT_OFF : 0) + (size_t)token * HDIM;
    int c = threadIdx.x * 4;
    *reinterpret_cast<float4*>(dst + c) = *reinterpret_cast<const float4*>(src + c);
  }
}

#define GLDS16(g, l) __builtin_amdgcn_global_load_lds( \
    (const __attribute__((address_space(1))) void*)(g), \
    (__attribute__((address_space(3))) void*)(l), 16, 0, 0)

// ---- tiled bf16 GEMM: C = relu(A @ B + bias); Bt is [N][K] ----
// 128x128 tile, 4 waves (2M x 2N, wave 64x64), BK=32, 3-slot LDS ring
// (36 KB -> 4 blocks/CU = 4 waves/SIMD: max measured-occupancy config).
// R6-proven loop: per iter {counted vmcnt(4) -> barrier -> 8 ds_read_b128
// -> refill freed slot (tile t+2) -> 16 MFMA (compiler lgkm waits)}.
// Never drain vmcnt to 0 mid-loop. R4-proven XOR swizzle (0 conflicts):
// phys chunk = content ^ ((row>>1)&3) via pre-swizzled global source.
// XCD-bijective block swizzle: M-panel p pinned to XCD p%8.
// MODE 0: bf16 store. MODE 1: LDS-staged f32x4 scatter via rowmap/order.
template<int MODE, int K>
__global__ __launch_bounds__(256, 4) void g128(
    const unsigned short* __restrict__ A, int M,
    const unsigned short* __restrict__ Bt, int N,
    const float* __restrict__ bias, int Nbias,
    unsigned short* __restrict__ Cbf, int ldc,
    float* __restrict__ outf, const int* __restrict__ order,
    int NP, int NC) {
  constexpr int NH = K / 32;
  __shared__ __align__(16) unsigned short S[3][8192];  // slot: A[128][32] | B[128][32]

  const int bid = blockIdx.x;
  const int r8 = bid & 7, rest = bid >> 3;
  const int c8 = rest % NC, q8 = rest / NC;
  const int p8 = q8 * 8 + r8;
  if (p8 >= NP) return;
  const int row0 = p8 * 128, col0 = c8 * 128;

  const int tid = threadIdx.x;
  const int wave = tid >> 6, lane = tid & 63;
  const int wm = wave >> 1, wn = wave & 1;
  const int fr = lane & 15, lch = lane >> 4;

  // staging: 16 segs of 16 rows (A 0..7, B 8..15); wave w -> segs 4w..4w+3
  const int lrow = lane >> 2;
  const int sswz = (((lane & 3) ^ ((lane >> 3) & 3)) << 3);
  const unsigned short* gp[4];
  int ldso[4];
  #pragma unroll
  for (int j = 0; j < 4; ++j) {
    const int g = wave * 4 + j;
    const bool isA = g < 8;
    int rr = isA ? (row0 + g * 16 + lrow) : (col0 + (g - 8) * 16 + lrow);
    const int lim = isA ? M : N;
    if (rr >= lim) rr = 0;
    gp[j] = (isA ? A : Bt) + (size_t)rr * K + sswz;
    ldso[j] = g * 512;                    // B segs land at 4096.. automatically
  }

  // fragment-read geometry (R4-proven swizzle)
  const int qoff = ((lch ^ ((fr >> 1) & 3)) << 3);
  const int abase = (wm * 64 + fr) * 32 + qoff;
  const int bbase = 4096 + (wn * 64 + fr) * 32 + qoff;

  f32x4 acc[4][4] = {};

  // prologue: stage tiles 0,1 into slots 0,1 (8 loads/wave)
  #pragma unroll
  for (int j = 0; j < 4; ++j) GLDS16(gp[j], S[0] + ldso[j]);
  #pragma unroll
  for (int j = 0; j < 4; ++j) GLDS16(gp[j] + 32, S[1] + ldso[j]);

  int cur = 0;
  #pragma unroll 1
  for (int t = 0; t < NH; ++t) {
    if (t + 1 < NH) asm volatile("s_waitcnt vmcnt(4)" ::: "memory");  // tile t landed
    else            asm volatile("s_waitcnt vmcnt(0)" ::: "memory");
    __builtin_amdgcn_s_barrier();
    __builtin_amdgcn_sched_barrier(0);
    const unsigned short* sl = S[cur];
    short8 a[4], b[4];
    #pragma unroll
    for (int m = 0; m < 4; ++m)
      a[m] = *reinterpret_cast<const short8*>(sl + abase + m * 512);
    #pragma unroll
    for (int n = 0; n < 4; ++n)
      b[n] = *reinterpret_cast<const short8*>(sl + bbase + n * 512);
    if (t + 2 < NH) {                    // refill freed slot (cur+2)%3 with tile t+2
      const int kc = (t + 2) * 32;
      int nb = cur + 2; if (nb >= 3) nb -= 3;
      #pragma unroll
      for (int j = 0; j < 4; ++j) GLDS16(gp[j] + kc, S[nb] + ldso[j]);
    }
    #pragma unroll
    for (int m = 0; m < 4; ++m)
      #pragma unroll
      for (int n = 0; n < 4; ++n)
        acc[m][n] = __builtin_amdgcn_mfma_f32_16x16x32_bf16(a[m], b[n], acc[m][n], 0, 0, 0);
    cur = (cur == 2) ? 0 : cur + 1;
  }

  // ---- epilogue ----
  const int orow = lch * 4;
  if (MODE == 0) {
    #pragma unroll
    for (int m = 0; m < 4; ++m)
      #pragma unroll
      for (int n = 0; n < 4; ++n)
        #pragma unroll
        for (int j = 0; j < 4; ++j) {
          int r = row0 + wm * 64 + m * 16 + orow + j;
          int c = col0 + wn * 64 + n * 16 + fr;
          if (r < M && c < N) {
            float v = acc[m][n][j] + (c < Nbias ? bias[c] : 0.f);
            Cbf[(size_t)r * ldc + c] = f2bf(fmaxf(v, 0.f));
          }
        }
  } else {
    // LDS-staged scatter: 2 bands of 64 rows; 512-B granule f32x4 writes.
    float* Cl = (float*)S;               // [64][132] f32 = 33.8 KB <= 48 KB
    #pragma unroll 1
    for (int p = 0; p < 2; ++p) {
      __builtin_amdgcn_s_barrier();      // band buffer free (all reads retired)
      if (wm == p) {                     // waves 2p, 2p+1 own this band
        #pragma unroll
        for (int m = 0; m < 4; ++m)
          #pragma unroll
          for (int n = 0; n < 4; ++n)
            #pragma unroll
            for (int j = 0; j < 4; ++j) {
              int rr = m * 16 + orow + j;          // 0..63
              int cc = wn * 64 + n * 16 + fr;      // 0..127
              float v = acc[m][n][j] + bias[col0 + cc];
              Cl[rr * 132 + cc] = fmaxf(v, 0.f);
            }
      }
      __builtin_amdgcn_s_barrier();      // band staged
      #pragma unroll
      for (int u = 0; u < 8; ++u) {
        int unit = tid + u * 256;        // 64 rows x 32 chunks = 2048 units
        int rr = unit >> 5, ch = unit & 31;
        int r = row0 + p * 64 + rr;
        if (r < M) {
          int iv, rk; rowmap(r, iv, rk);
          int token = order[rk];
          f32x4 v = *reinterpret_cast<const f32x4*>(Cl + rr * 132 + ch * 4);
          *reinterpret_cast<f32x4*>(outf + (size_t)(iv ? OUT_OFF : 0) +
                                    (size_t)token * HDIM + col0 + ch * 4) = v;
        }
      }
    }
  }
}

static inline int swzg(int NP, int NC) { return 8 * NC * ((NP + 7) / 8); }

extern "C" void kernel_launch(void* const* d_in, const int* in_sizes, int n_in,
                              void* d_out, int out_size, void* d_ws, size_t ws_size,
                              hipStream_t stream) {
  const float* keys   = (const float*)d_in[0];
  const float* values = (const float*)d_in[1];
  const float* imp    = (const float*)d_in[2];
  const float* We0    = (const float*)d_in[3];
  const float* be0    = (const float*)d_in[4];
  const float* We1    = (const float*)d_in[5];
  const float* be1    = (const float*)d_in[6];
  const float* Wd0    = (const float*)d_in[7];
  const float* bd0    = (const float*)d_in[8];
  const float* Wd1    = (const float*)d_in[9];
  const float* bd1    = (const float*)d_in[10];

  char* ws = (char*)d_ws;
  int* counts           = (int*)(ws);                       // 64 KB
  int* order            = (int*)(ws + 65536);               // 64 KB
  unsigned short* We0T  = (unsigned short*)(ws + 131072);   // [512][1024]
  unsigned short* We1T  = (unsigned short*)(ws + 1179648);  // [256][512], rows 204+ zero
  unsigned short* Wd1T  = (unsigned short*)(ws + 1441792);  // [512][256], cols 204+ zero
  unsigned short* Wd0T  = (unsigned short*)(ws + 1703936);  // [1024][512]
  unsigned short* Y     = (unsigned short*)(ws + 2752512);  // [26216][512]
  unsigned short* Z     = (unsigned short*)(ws + 29597696); // [22022][256]
  unsigned short* X     = (unsigned short*)(ws + 40872960); // [26216][1024]
  float* outf = (float*)d_out;

  hipMemsetAsync(counts, 0, 65536, stream);
  rank_count<<<dim3(64, 8), 256, 0, stream>>>(imp, counts);
  scatter_order<<<64, 256, 0, stream>>>(counts, order);

  // fused: weight converts + gather + level-0 copy (one launch)
  prep_fused<<<5120 + M1ROWS + 6552, 256, 0, stream>>>(
      We0T, We0, We1T, We1, Wd1T, Wd1, Wd0T, Wd0, X, keys, values, order, outf);

  // GEMM1: Y = relu(X @ We0 + be0)   [26216 x 1024] x [1024 x 512]
  g128<0, 1024><<<swzg(205, 4), 256, 0, stream>>>(
      X, M1ROWS, We0T, 512, be0, 512, Y, 512, nullptr, nullptr, 205, 4);

  // GEMM2a: Z = relu(Y_l2 @ We1 + be1)  [22022 x 512] x [512 x 256pad]
  g128<0, 512><<<swzg(173, 2), 256, 0, stream>>>(
      Y + (size_t)L2ROW0 * 512, M2ROWS, We1T, 256, be1, 204, Z, 256,
      nullptr, nullptr, 173, 2);

  // GEMM2b: Y_l2 = relu(Z @ Wd1 + bd1)  [22022 x 256] x [256 x 512]
  g128<0, 256><<<swzg(173, 4), 256, 0, stream>>>(
      Z, M2ROWS, Wd1T, 512, bd1, 512, Y + (size_t)L2ROW0 * 512, 512,
      nullptr, nullptr, 173, 4);

  // GEMM3: out = relu(Y @ Wd0 + bd0), LDS-staged f32x4 scatter
  g128<1, 512><<<swzg(205, 8), 256, 0, stream>>>(
      Y, M1ROWS, Wd0T, 1024, bd0, 1024, nullptr, 0, outf, order, 205, 8);
}